// Round 9
// baseline (146.588 us; speedup 1.0000x reference)
//
#include <hip/hip_runtime.h>
#include <hip/hip_bf16.h>
#include <stdint.h>

// QuantConv2d on MI355X — int8, 2-kernel fused pipeline.
// k_prep:  per-block partial max|x| + weight quantization to int8 (exact IEEE div, half-even).
// k_fused: re-reduce partials -> xscale; quantize the block's x-halo tile into LDS
//          (NCHW -> [row][px][ci] int8, px-stride 40B = 2-way banks), then implicit-GEMM
//          3x3 conv with mfma_i32_32x32x32_i8 (one tap per MFMA), i32 accum, fused
//          dequant+bias epilogue. No qx round-trip, no third dispatch.
// Exactness: q values are ints in [-127,127] (exact in i8); i32 accumulation is exact and
// equals the reference's fp32 einsum since every partial sum < 2^24.

typedef int i32x2  __attribute__((ext_vector_type(2)));
typedef int i32x4  __attribute__((ext_vector_type(4)));
typedef int i32x16 __attribute__((ext_vector_type(16)));

#define CIN   32
#define COUT  32
#define HH    224
#define WW    224
#define NB    8
#define QMAXF 127.0f

#define RED_BLOCKS 1024
#define PF_OFF  16                 // float idx of partial maxes in ws
#define QW_OFF  8192               // byte offset of qw (int8 [32][288])

#define RT   8                     // output rows per block
#define SR   10                    // staged rows (RT + 2 halo)
#define SW   34                    // staged px   (32 + 2 halo)
#define PXS  10                    // px stride in WORDS (40 B: 32 ci + 8 pad -> 2-way banks)

// ws layout: ws[1]=bits of wscale, float ws[PF_OFF..PF_OFF+1024) = per-block partial
// max|x|, byte QW_OFF: qw int8 [COUT][9][32] (k=(kh*3+kw)*32+ci).

__global__ __launch_bounds__(256) void k_prep(const float* __restrict__ x, int n4,
                                              const float* __restrict__ wgt,
                                              unsigned* __restrict__ ws) {
    const int tid = threadIdx.x;
    __shared__ float red[4];
    if (blockIdx.x < RED_BLOCKS) {
        const float4* x4 = (const float4*)x;
        float m = 0.f;
        for (int i = blockIdx.x * 256 + tid; i < n4; i += RED_BLOCKS * 256) {
            float4 v = x4[i];
            m = fmaxf(m, fmaxf(fmaxf(fabsf(v.x), fabsf(v.y)), fmaxf(fabsf(v.z), fabsf(v.w))));
        }
        #pragma unroll
        for (int off = 32; off >= 1; off >>= 1) m = fmaxf(m, __shfl_xor(m, off));
        if ((tid & 63) == 0) red[tid >> 6] = m;
        __syncthreads();
        if (tid == 0)
            ((float*)ws)[PF_OFF + blockIdx.x] =
                fmaxf(fmaxf(red[0], red[1]), fmaxf(red[2], red[3]));
    } else {
        // single block: max|w| -> wscale, pre-quantize weights to int8.
        float m = 0.f;
        for (int i = tid; i < COUT * CIN * 9; i += 256) m = fmaxf(m, fabsf(wgt[i]));
        #pragma unroll
        for (int off = 32; off >= 1; off >>= 1) m = fmaxf(m, __shfl_xor(m, off));
        if ((tid & 63) == 0) red[tid >> 6] = m;
        __syncthreads();
        const float mw = fmaxf(fmaxf(red[0], red[1]), fmaxf(red[2], red[3]));
        const float wscale = mw / QMAXF;
        if (tid == 0) ws[1] = __float_as_uint(wscale);
        signed char* qw = (signed char*)ws + QW_OFF;
        for (int e = tid; e < COUT * 288; e += 256) {
            const int co = e / 288, k = e % 288;
            const int t = k >> 5, ci = k & 31;
            const int kh = t / 3, kw = t % 3;
            const float v = wgt[((co * CIN + ci) * 3 + kh) * 3 + kw];
            float q = rintf(v / wscale);                  // IEEE div + half-even == jnp
            q = fminf(fmaxf(q, -QMAXF), QMAXF);
            qw[e] = (signed char)(int)q;                  // exact small int
        }
    }
}

// Fused quantize + conv. Block = 1 w-tile (32 px) x 8 output rows; wave = 2 rows.
// Stage: thread task (row, ci0-quad, px) reads 4 NCHW planes (coalesced across px),
//        quantizes (exact IEEE div + rintf), packs 4 bytes, one ds_write_b32.
// Conv:  B-frag lane(px=lane&31, hi=lane>>5) = LDS 16B at (row*34+px)*40 + hi*16,
//        read as two i32x2 (8B-aligned). A frag from global qw (R7-proven layout).
// C/D:   col(px)=lane&31, row(co)=(reg&3)+8*(reg>>2)+4*(lane>>5)  [guide m74/m101].
__global__ __launch_bounds__(256) void k_fused(const float* __restrict__ x,
                                               const signed char* __restrict__ qw,
                                               const float* __restrict__ bias,
                                               const unsigned* __restrict__ ws,
                                               float* __restrict__ out) {
    __shared__ int lds[SR * SW * PXS];                   // 13,600 B
    __shared__ float red[4];

    const int tid  = threadIdx.x;
    const int lane = tid & 63;
    const int wv   = tid >> 6;
    const int w0   = (blockIdx.x % 7) * 32;
    const int hb   = ((blockIdx.x / 7) % 28) * 8;
    const int b    = blockIdx.x / (7 * 28);
    const int col  = lane & 31;                   // pixel for B/D, cout row for A
    const int hi   = lane >> 5;

    // re-reduce the 1024 partial maxes -> xscale (identical in every block)
    const float* pf = (const float*)ws + PF_OFF;
    float m = 0.f;
    for (int i = tid; i < RED_BLOCKS; i += 256) m = fmaxf(m, pf[i]);
    #pragma unroll
    for (int off = 32; off >= 1; off >>= 1) m = fmaxf(m, __shfl_xor(m, off));
    if ((tid & 63) == 0) red[tid >> 6] = m;
    __syncthreads();
    const float xscale =
        fmaxf(fmaxf(red[0], red[1]), fmaxf(red[2], red[3])) / QMAXF;
    const float s = xscale * __uint_as_float(ws[1]);

    // A fragments from global qw (L2-served), issued before staging completes
    i32x4 afr[9];
    #pragma unroll
    for (int t = 0; t < 9; ++t)
        afr[t] = *(const i32x4*)&qw[col * 288 + t * 32 + hi * 16];

    // ---- stage + quantize the halo tile: 10 rows x 34 px x 32 ci ----
    // task = (row*8 + ci0)*34 + px ; px innermost across lanes -> coalesced loads
    #pragma unroll
    for (int it = 0; it < 11; ++it) {
        const int t = it * 256 + tid;
        if (t < SR * 8 * SW) {
            const int px  = t % SW;
            const int q2  = t / SW;
            const int ci0 = q2 & 7;
            const int row = q2 >> 3;
            const int hg  = hb - 1 + row;
            const int wg  = w0 - 1 + px;
            unsigned pack = 0u;
            if ((unsigned)hg < HH && (unsigned)wg < WW) {
                const float* xp =
                    x + ((size_t)(b * CIN + ci0 * 4) * HH + hg) * WW + wg;
                #pragma unroll
                for (int j = 0; j < 4; ++j) {
                    const float v = xp[j * (HH * WW)];
                    float q = rintf(v / xscale);          // exact IEEE div, half-even
                    q = fminf(fmaxf(q, -QMAXF), QMAXF);
                    pack |= ((unsigned)((int)q & 0xff)) << (8 * j);
                }
            }
            lds[(row * SW + px) * PXS + ci0] = (int)pack;
        }
    }
    __syncthreads();

    // ---- conv: wave handles output rows hb + wv*2 + {0,1} ----
    i32x16 acc0 = {0,0,0,0,0,0,0,0,0,0,0,0,0,0,0,0};
    i32x16 acc1 = {0,0,0,0,0,0,0,0,0,0,0,0,0,0,0,0};

    const int r0 = wv * 2;                        // staged row of (out row, kh=0)... r = r0+kh
    #pragma unroll
    for (int pr = 0; pr < 4; ++pr) {
        #pragma unroll
        for (int kw = 0; kw < 3; ++kw) {
            const int widx = ((r0 + pr) * SW + col + kw) * PXS + hi * 4;
            const i32x2 lo = *(const i32x2*)&lds[widx];
            const i32x2 hi2 = *(const i32x2*)&lds[widx + 2];
            const i32x4 bf = {lo[0], lo[1], hi2[0], hi2[1]};
            if (pr <= 2)                          // out row +0, kh = pr
                acc0 = __builtin_amdgcn_mfma_i32_32x32x32_i8(afr[pr * 3 + kw], bf, acc0, 0, 0, 0);
            if (pr >= 1)                          // out row +1, kh = pr-1
                acc1 = __builtin_amdgcn_mfma_i32_32x32x32_i8(afr[(pr - 1) * 3 + kw], bf, acc1, 0, 0, 0);
        }
    }

    // epilogue: dequant + bias
    const int h = hb + wv * 2;
    const size_t hw0 = (size_t)h * WW + w0 + col;
    #pragma unroll
    for (int r = 0; r < 16; ++r) {
        const int co = (r & 3) + 8 * (r >> 2) + 4 * hi;
        const float bv = bias[co];
        float* op = out + (size_t)(b * COUT + co) * (HH * WW) + hw0;
        op[0]  = (float)acc0[r] * s + bv;
        op[WW] = (float)acc1[r] * s + bv;
    }
}

extern "C" void kernel_launch(void* const* d_in, const int* in_sizes, int n_in,
                              void* d_out, int out_size, void* d_ws, size_t ws_size,
                              hipStream_t stream) {
    const float* x    = (const float*)d_in[0];
    const float* wgt  = (const float*)d_in[1];
    const float* bias = (const float*)d_in[2];
    float* out        = (float*)d_out;
    unsigned* ws      = (unsigned*)d_ws;
    const signed char* qw = (const signed char*)d_ws + QW_OFF;

    const int n4 = in_sizes[0] / 4;
    k_prep <<<RED_BLOCKS + 1, 256, 0, stream>>>(x, n4, wgt, ws);
    k_fused<<<NB * 28 * 7, 256, 0, stream>>>(x, qw, bias, ws, out);
}

// Round 10
// 133.129 us; speedup vs baseline: 1.1011x; 1.1011x over previous
//
#include <hip/hip_runtime.h>
#include <hip/hip_bf16.h>
#include <stdint.h>

// QuantConv2d on MI355X — int8 end-to-end, 3-kernel pipeline (R7 structure).
// k_prep: per-block partial max|x| + weight quantization to int8 (exact IEEE div, half-even).
// k_quant: re-reduce partials -> xscale; x (NCHW f32) -> qx (padded NHWC int8), exact.
// k_conv: implicit-GEMM 3x3 conv, mfma_i32_32x32x32_i8, 4 output rows/wave (B-frag
//         reuse 1 load : 2 MFMA), i32 accum, fused dequant+bias epilogue.
// Exactness: q values are ints in [-127,127] (exact in i8); i32 accumulation is exact and
// equals the reference's fp32 einsum since every partial sum < 2^24.

typedef int i32x4  __attribute__((ext_vector_type(4)));
typedef int i32x16 __attribute__((ext_vector_type(16)));

#define CIN   32
#define COUT  32
#define HH    224
#define WW    224
#define NB    8
#define QMAXF 127.0f
#define PP    226            // padded spatial dim (1-px zero border)

#define RED_BLOCKS 1024
#define PF_OFF  16                                       // float idx of partial maxes
#define QW_OFF  8192                                     // byte offset of qw (int8 [32][288])
#define QX_OFF  32768                                    // byte offset of qx (int8 NHWC padded)

// ws layout: ws[0]=bits of xscale (written by k_quant), ws[1]=bits of wscale,
// float ws[PF_OFF..PF_OFF+1024) = per-block partial max|x|,
// byte QW_OFF: qw int8 [COUT][9][32] (k=(kh*3+kw)*32+ci),
// byte QX_OFF: qx int8 [NB][PP][PP][CIN] zero-padded NHWC.

__global__ __launch_bounds__(256) void k_prep(const float* __restrict__ x, int n4,
                                              const float* __restrict__ wgt,
                                              unsigned* __restrict__ ws) {
    const int tid = threadIdx.x;
    __shared__ float red[4];
    if (blockIdx.x < RED_BLOCKS) {
        const float4* x4 = (const float4*)x;
        float m = 0.f;
        for (int i = blockIdx.x * 256 + tid; i < n4; i += RED_BLOCKS * 256) {
            float4 v = x4[i];
            m = fmaxf(m, fmaxf(fmaxf(fabsf(v.x), fabsf(v.y)), fmaxf(fabsf(v.z), fabsf(v.w))));
        }
        #pragma unroll
        for (int off = 32; off >= 1; off >>= 1) m = fmaxf(m, __shfl_xor(m, off));
        if ((tid & 63) == 0) red[tid >> 6] = m;
        __syncthreads();
        if (tid == 0)
            ((float*)ws)[PF_OFF + blockIdx.x] =
                fmaxf(fmaxf(red[0], red[1]), fmaxf(red[2], red[3]));
    } else {
        // single block: max|w| -> wscale, pre-quantize weights to int8.
        float m = 0.f;
        for (int i = tid; i < COUT * CIN * 9; i += 256) m = fmaxf(m, fabsf(wgt[i]));
        #pragma unroll
        for (int off = 32; off >= 1; off >>= 1) m = fmaxf(m, __shfl_xor(m, off));
        if ((tid & 63) == 0) red[tid >> 6] = m;
        __syncthreads();
        const float mw = fmaxf(fmaxf(red[0], red[1]), fmaxf(red[2], red[3]));
        const float wscale = mw / QMAXF;
        if (tid == 0) ws[1] = __float_as_uint(wscale);
        signed char* qw = (signed char*)ws + QW_OFF;
        for (int e = tid; e < COUT * 288; e += 256) {
            const int co = e / 288, k = e % 288;
            const int t = k >> 5, ci = k & 31;
            const int kh = t / 3, kw = t % 3;
            const float v = wgt[((co * CIN + ci) * 3 + kh) * 3 + kw];
            float q = rintf(v / wscale);                  // IEEE div + half-even == jnp
            q = fminf(fmaxf(q, -QMAXF), QMAXF);
            qw[e] = (signed char)(int)q;                  // exact small int
        }
    }
}

// x (NCHW fp32) -> qx (padded NHWC int8). One int4 (16 ci at one pixel) per thread-iter.
__global__ __launch_bounds__(256) void k_quant(const float* __restrict__ x,
                                               unsigned* __restrict__ ws,
                                               signed char* __restrict__ qx) {
    // block-local re-reduction of the 1024 partial maxes (identical in every block)
    __shared__ float red[4];
    const float* pf = (const float*)ws + PF_OFF;
    float m = 0.f;
    for (int i = threadIdx.x; i < RED_BLOCKS; i += 256) m = fmaxf(m, pf[i]);
    #pragma unroll
    for (int off = 32; off >= 1; off >>= 1) m = fmaxf(m, __shfl_xor(m, off));
    if ((threadIdx.x & 63) == 0) red[threadIdx.x >> 6] = m;
    __syncthreads();
    const float xscale =
        fmaxf(fmaxf(red[0], red[1]), fmaxf(red[2], red[3])) / QMAXF;
    if (blockIdx.x == 0 && threadIdx.x == 0) ws[0] = __float_as_uint(xscale);

    const int total = NB * PP * PP * 2;                  // int4 (16-byte) stores
    for (int o16 = blockIdx.x * 256 + threadIdx.x; o16 < total; o16 += gridDim.x * 256) {
        const int half = o16 & 1;
        int t = o16 >> 1;
        const int wp = t % PP; t /= PP;
        const int hp = t % PP;
        const int b  = t / PP;
        union { signed char c[16]; int4 v; } u;
        u.v = make_int4(0, 0, 0, 0);
        if (hp != 0 && hp != PP - 1 && wp != 0 && wp != PP - 1) {
            const float* xp =
                x + ((size_t)(b * CIN + half * 16) * HH + (hp - 1)) * WW + (wp - 1);
            #pragma unroll
            for (int c = 0; c < 16; ++c) {
                const float v = xp[c * (HH * WW)];
                float q = rintf(v / xscale);              // exact IEEE div, half-even
                q = fminf(fmaxf(q, -QMAXF), QMAXF);
                u.c[c] = (signed char)(int)q;
            }
        }
        ((int4*)qx)[o16] = u.v;
    }
}

// Implicit-GEMM conv. Block = 1 w-tile (32 px) x 16 output rows; wave = 4 rows.
// mfma_i32_32x32x32_i8: one MFMA = 32co x 32px x one tap (32 ci).
// Wave walks 6 shared padded rows x 3 kw = 18 B-loads feeding 36 MFMAs (1 load : 2 MFMA).
// A frag: lane holds qw[co=lane&31][tap t][ci=(lane>>5)*16 + 0..15] (contiguous 16B).
// B frag: lane holds qx[row][px=w0+(lane&31)+kw][ci=(lane>>5)*16 + 0..15].
// C/D:    col(px)=lane&31, row(co)=(reg&3)+8*(reg>>2)+4*(lane>>5)  [guide m74/m101; R7-verified].
__global__ __launch_bounds__(256) void k_conv(const signed char* __restrict__ qx,
                                              const signed char* __restrict__ qw,
                                              const float* __restrict__ bias,
                                              const unsigned* __restrict__ ws,
                                              float* __restrict__ out) {
    const int tid  = threadIdx.x;
    const int lane = tid & 63;
    const int wv   = tid >> 6;
    const int w0   = (blockIdx.x % 7) * 32;
    const int hb   = ((blockIdx.x / 7) % 14) * 16;
    const int b    = blockIdx.x / (7 * 14);
    const int h    = hb + wv * 4;                 // this wave's first output row
    const int col  = lane & 31;                   // pixel for B/D, cout row for A
    const int hi   = lane >> 5;

    const float s = __uint_as_float(ws[0]) * __uint_as_float(ws[1]);

    i32x4 afr[9];
    #pragma unroll
    for (int t = 0; t < 9; ++t)
        afr[t] = *(const i32x4*)&qw[col * 288 + t * 32 + hi * 16];

    const i32x16 zero = {0,0,0,0,0,0,0,0,0,0,0,0,0,0,0,0};
    i32x16 acc[4] = {zero, zero, zero, zero};

    // padded row for (out h+o, kh) is h+o+kh; rows h..h+5 cover all 4 output rows.
    const signed char* base =
        qx + (((size_t)b * PP + h) * PP + (w0 + col)) * CIN + hi * 16;
    #pragma unroll
    for (int pr = 0; pr < 6; ++pr) {
        #pragma unroll
        for (int kw = 0; kw < 3; ++kw) {
            const i32x4 bf = *(const i32x4*)(base + (pr * PP + kw) * CIN);
            #pragma unroll
            for (int o = 0; o < 4; ++o) {
                if (pr >= o && pr <= o + 2)       // kh = pr - o in [0,2]; folds at compile time
                    acc[o] = __builtin_amdgcn_mfma_i32_32x32x32_i8(
                        afr[(pr - o) * 3 + kw], bf, acc[o], 0, 0, 0);
            }
        }
    }

    // epilogue: dequant + bias
    const size_t hw0 = (size_t)h * WW + w0 + col;
    #pragma unroll
    for (int r = 0; r < 16; ++r) {
        const int co = (r & 3) + 8 * (r >> 2) + 4 * hi;
        const float bv = bias[co];
        float* op = out + (size_t)(b * COUT + co) * (HH * WW) + hw0;
        #pragma unroll
        for (int o = 0; o < 4; ++o)
            op[o * WW] = (float)acc[o][r] * s + bv;
    }
}

extern "C" void kernel_launch(void* const* d_in, const int* in_sizes, int n_in,
                              void* d_out, int out_size, void* d_ws, size_t ws_size,
                              hipStream_t stream) {
    const float* x    = (const float*)d_in[0];
    const float* wgt  = (const float*)d_in[1];
    const float* bias = (const float*)d_in[2];
    float* out        = (float*)d_out;
    unsigned* ws      = (unsigned*)d_ws;
    const signed char* qw = (const signed char*)d_ws + QW_OFF;
    signed char* qx       = (signed char*)d_ws + QX_OFF;

    const int n4 = in_sizes[0] / 4;
    k_prep <<<RED_BLOCKS + 1, 256, 0, stream>>>(x, n4, wgt, ws);
    k_quant<<<3200, 256, 0, stream>>>(x, ws, qx);
    k_conv <<<NB * 14 * 7, 256, 0, stream>>>(qx, qw, bias, ws, out);
}